// Round 1
// baseline (286.573 us; speedup 1.0000x reference)
//
#include <hip/hip_runtime.h>

// Problem constants
#define BB 2
#define SS 512
#define EE 1024
#define GG 4
#define HH 8
#define QQn 16
#define DD 2
#define VV 16
#define NN 512
// derived: S*D = 1024, B*S = 1024, G*Q*H*D = 1024, G*V*H*D = 1024

// ---------------------------------------------------------------------------
// Kernel 1: transpose keys/values into attention-friendly layout.
// keys  [B,G,N,Q*H] -> KT[bgh][q4][n][4]  (float4 per (q-group, n))
// values[B,G,N,V*H] -> VT[bgh][v4][n][4]
// ---------------------------------------------------------------------------
__global__ __launch_bounds__(256) void kv_transpose(
    const float* __restrict__ keys, const float* __restrict__ values,
    float* __restrict__ KT, float* __restrict__ VT) {
  const int bg = blockIdx.y;   // 0..7  (b*4+g)
  const int nb = blockIdx.x;   // 0..7  (64-row n block)
  const int tid = threadIdx.x;
  const long src_base = (long)bg * 512 * 128 + (long)nb * 64 * 128;
#pragma unroll
  for (int i = 0; i < 8; ++i) {
    int idx = tid + i * 256;            // 0..2047 float4s (64 rows x 32 f4)
    int nl = idx >> 5, c4 = idx & 31;
    int n = nb * 64 + nl;
    float4 kv = *reinterpret_cast<const float4*>(&keys[src_base + nl * 128 + c4 * 4]);
    float4 vv = *reinterpret_cast<const float4*>(&values[src_base + nl * 128 + c4 * 4]);
#pragma unroll
    for (int cc = 0; cc < 4; ++cc) {
      int col = c4 * 4 + cc;
      int h = col & 7, qv = col >> 3;   // qq (or vv) in 0..15
      long dst = ((long)(bg * 8 + h) * 4 + (qv >> 2)) * 2048 + n * 4 + (qv & 3);
      float kval = (cc == 0) ? kv.x : (cc == 1) ? kv.y : (cc == 2) ? kv.z : kv.w;
      float vval = (cc == 0) ? vv.x : (cc == 1) ? vv.y : (cc == 2) ? vv.z : vv.w;
      KT[dst] = kval;
      VT[dst] = vval;
    }
  }
}

// ---------------------------------------------------------------------------
// Kernel 2/5: f32 GEMM, C[1024,1024] = A[1024,1024] @ B[1024,1024] + bias.
// MODE 0: plain row-major store (final projection).
// MODE 1: q-projection — scatter-store into qT[bgh][sd][qq] layout.
// 64x64 tile, 256 threads, 4x4 per thread, BK=16.
// ---------------------------------------------------------------------------
template <int MODE>
__global__ __launch_bounds__(256) void gemm1024(
    const float* __restrict__ A, const float* __restrict__ Bm,
    const float* __restrict__ bias, float* __restrict__ C) {
  __shared__ float As[16][64];
  __shared__ float Bs[16][64];
  const int tid = threadIdx.x;
  const int tx = tid & 15, ty = tid >> 4;
  const int brow = blockIdx.y * 64, bcol = blockIdx.x * 64;

  const int arow = tid >> 2;        // 0..63
  const int ak4 = (tid & 3) * 4;    // 0,4,8,12
  const int bkrow = tid >> 4;       // 0..15
  const int bcol4 = (tid & 15) * 4;

  float acc[4][4] = {};

  for (int kt = 0; kt < 1024; kt += 16) {
    float4 a4 = *reinterpret_cast<const float4*>(&A[(brow + arow) * 1024 + kt + ak4]);
    float4 b4 = *reinterpret_cast<const float4*>(&Bm[(kt + bkrow) * 1024 + bcol + bcol4]);
    __syncthreads();
    As[ak4 + 0][arow] = a4.x;
    As[ak4 + 1][arow] = a4.y;
    As[ak4 + 2][arow] = a4.z;
    As[ak4 + 3][arow] = a4.w;
    *reinterpret_cast<float4*>(&Bs[bkrow][bcol4]) = b4;
    __syncthreads();
#pragma unroll
    for (int kk = 0; kk < 16; ++kk) {
      float4 av = *reinterpret_cast<const float4*>(&As[kk][ty * 4]);
      float4 bv = *reinterpret_cast<const float4*>(&Bs[kk][tx * 4]);
      float am[4] = {av.x, av.y, av.z, av.w};
      float bm[4] = {bv.x, bv.y, bv.z, bv.w};
#pragma unroll
      for (int i = 0; i < 4; ++i)
#pragma unroll
        for (int j = 0; j < 4; ++j) acc[i][j] += am[i] * bm[j];
    }
  }

  if (MODE == 0) {
#pragma unroll
    for (int i = 0; i < 4; ++i) {
      float4 o;
      o.x = acc[i][0] + bias[bcol + tx * 4 + 0];
      o.y = acc[i][1] + bias[bcol + tx * 4 + 1];
      o.z = acc[i][2] + bias[bcol + tx * 4 + 2];
      o.w = acc[i][3] + bias[bcol + tx * 4 + 3];
      *reinterpret_cast<float4*>(&C[(brow + ty * 4 + i) * 1024 + bcol + tx * 4]) = o;
    }
  } else {
    // scatter into qT[bgh][sd][qq]:
    //   b = row>>9, s = row&511, g = s>>7
    //   h = c&7, qq = (c>>3)&15, sd = (s&127)*8 + (c>>7)
#pragma unroll
    for (int i = 0; i < 4; ++i) {
      int row = brow + ty * 4 + i;
      int b = row >> 9, s = row & 511, g = s >> 7;
#pragma unroll
      for (int j = 0; j < 4; ++j) {
        int colc = bcol + tx * 4 + j;
        float v = acc[i][j] + bias[colc];
        int h = colc & 7, qqi = (colc >> 3) & 15, chi = colc >> 7;
        int sd = (s & 127) * 8 + chi;
        int bgh = b * 32 + g * 8 + h;
        C[((long)bgh * 1024 + sd) * 16 + qqi] = v;
      }
    }
  }
}

// ---------------------------------------------------------------------------
// Kernel 3: fused attention per (bgh, 64-row block).
//   scores = qT[bgh] @ KT[bgh]^T * 0.25 - conn_sub ; softmax ; @ VT[bgh]
//   -> ln_in[b][ss][g*256 + h*32 + dd*16 + vv]   (sd = dd*512 + ss)
// Block: 256 threads = 4 waves; each wave owns one row at a time.
// Lane l handles keys n = j*64 + l (j = 0..7).
// ---------------------------------------------------------------------------
__global__ __launch_bounds__(256) void attn_kernel(
    const float* __restrict__ qT, const float* __restrict__ KT,
    const float* __restrict__ VT, const float* __restrict__ conn,
    float* __restrict__ ln_in) {
  __shared__ float4 K4[4][512];   // K4[q4][n] = K[n][q4*4..+3]
  __shared__ float4 V4[4][512];
  __shared__ float Qs[64][16];

  const int tid = threadIdx.x;
  const int rb = blockIdx.x;      // 0..15 row block
  const int bgh = blockIdx.y;     // 0..63
  const int b = bgh >> 5, g = (bgh >> 3) & 3, h = bgh & 7;

  // stage K, V (coalesced float4 copies from pre-transposed layout)
  const float4* ksrc = reinterpret_cast<const float4*>(KT) + (long)bgh * 2048;
  const float4* vsrc = reinterpret_cast<const float4*>(VT) + (long)bgh * 2048;
  float4* k4f = &K4[0][0];
  float4* v4f = &V4[0][0];
#pragma unroll
  for (int i = 0; i < 8; ++i) {
    int idx = tid + i * 256;
    k4f[idx] = ksrc[idx];
    v4f[idx] = vsrc[idx];
  }
  // stage Q rows for this block (coalesced)
  const float* qsrc = qT + (long)bgh * 16384 + rb * 64 * 16;
  float* qsf = &Qs[0][0];
#pragma unroll
  for (int i = 0; i < 4; ++i) {
    int idx = tid + i * 256;
    qsf[idx] = qsrc[idx];
  }
  __syncthreads();

  const int lane = tid & 63, wid = tid >> 6;

  for (int r16 = 0; r16 < 16; ++r16) {
    const int r = r16 * 4 + wid;
    const int sd = rb * 64 + r;
    const long cbase = ((long)bgh * 1024 + sd) * 512;

    // prefetch conn_sub row slice (the dominant HBM stream, coalesced)
    float cs[8];
#pragma unroll
    for (int j = 0; j < 8; ++j) cs[j] = conn[cbase + j * 64 + lane];

    // scores: dot(q_row[16], K[n][16]) for this lane's 8 keys
    float sc[8];
#pragma unroll
    for (int j = 0; j < 8; ++j) sc[j] = 0.f;
#pragma unroll
    for (int q4 = 0; q4 < 4; ++q4) {
      float4 qv = *reinterpret_cast<const float4*>(&Qs[r][q4 * 4]);
#pragma unroll
      for (int j = 0; j < 8; ++j) {
        float4 kv = K4[q4][j * 64 + lane];
        sc[j] += qv.x * kv.x + qv.y * kv.y + qv.z * kv.z + qv.w * kv.w;
      }
    }

    // bias + softmax (wave-parallel over the 512 keys)
    float m = -1e30f;
#pragma unroll
    for (int j = 0; j < 8; ++j) {
      sc[j] = sc[j] * 0.25f - cs[j];
      m = fmaxf(m, sc[j]);
    }
#pragma unroll
    for (int w = 32; w >= 1; w >>= 1) m = fmaxf(m, __shfl_xor(m, w, 64));
    float sum = 0.f;
#pragma unroll
    for (int j = 0; j < 8; ++j) {
      sc[j] = __expf(sc[j] - m);
      sum += sc[j];
    }
#pragma unroll
    for (int w = 32; w >= 1; w >>= 1) sum += __shfl_xor(sum, w, 64);
    const float inv = 1.0f / sum;
#pragma unroll
    for (int j = 0; j < 8; ++j) sc[j] *= inv;

    // PV: o[vv] = sum_n p[n] * V[n][vv]
    float o[16];
#pragma unroll
    for (int vv = 0; vv < 16; ++vv) o[vv] = 0.f;
#pragma unroll
    for (int vg = 0; vg < 4; ++vg) {
#pragma unroll
      for (int j = 0; j < 8; ++j) {
        float4 v4 = V4[vg][j * 64 + lane];
        o[vg * 4 + 0] += sc[j] * v4.x;
        o[vg * 4 + 1] += sc[j] * v4.y;
        o[vg * 4 + 2] += sc[j] * v4.z;
        o[vg * 4 + 3] += sc[j] * v4.w;
      }
    }
    // butterfly-reduce each of the 16 partials across the 64 lanes
#pragma unroll
    for (int vv = 0; vv < 16; ++vv) {
#pragma unroll
      for (int w = 32; w >= 1; w >>= 1) o[vv] += __shfl_xor(o[vv], w, 64);
    }

    // write: ch = g*256 + h*32 + dd*16 + vv ; sd = dd*512 + ss
    const int dd = sd >> 9, ssi = sd & 511;
    const int chbase = g * 256 + h * 32 + dd * 16;
    float val = o[0];
#pragma unroll
    for (int vv = 1; vv < 16; ++vv)
      if (lane == vv) val = o[vv];
    if (lane < 16) ln_in[(long)(b * 512 + ssi) * 1024 + chbase + lane] = val;
  }
}

// ---------------------------------------------------------------------------
// Kernel 4: in-place LayerNorm over last dim (1024), one block per row.
// ---------------------------------------------------------------------------
__global__ __launch_bounds__(256) void ln_kernel(
    float* __restrict__ x, const float* __restrict__ gamma,
    const float* __restrict__ beta) {
  const int row = blockIdx.x;
  const int tid = threadIdx.x;
  float4 v = *reinterpret_cast<const float4*>(&x[(long)row * 1024 + tid * 4]);
  float s = v.x + v.y + v.z + v.w;
  float s2 = v.x * v.x + v.y * v.y + v.z * v.z + v.w * v.w;
#pragma unroll
  for (int w = 32; w >= 1; w >>= 1) {
    s += __shfl_xor(s, w, 64);
    s2 += __shfl_xor(s2, w, 64);
  }
  __shared__ float red[8];
  const int lane = tid & 63, wid = tid >> 6;
  if (lane == 0) {
    red[wid] = s;
    red[wid + 4] = s2;
  }
  __syncthreads();
  s = red[0] + red[1] + red[2] + red[3];
  s2 = red[4] + red[5] + red[6] + red[7];
  const float mu = s * (1.0f / 1024.0f);
  const float var = s2 * (1.0f / 1024.0f) - mu * mu;
  const float rstd = rsqrtf(var + 1e-5f);
  float4 g4 = *reinterpret_cast<const float4*>(&gamma[tid * 4]);
  float4 b4 = *reinterpret_cast<const float4*>(&beta[tid * 4]);
  float4 o;
  o.x = (v.x - mu) * rstd * g4.x + b4.x;
  o.y = (v.y - mu) * rstd * g4.y + b4.y;
  o.z = (v.z - mu) * rstd * g4.z + b4.z;
  o.w = (v.w - mu) * rstd * g4.w + b4.w;
  *reinterpret_cast<float4*>(&x[(long)row * 1024 + tid * 4]) = o;
}

// ---------------------------------------------------------------------------
extern "C" void kernel_launch(void* const* d_in, const int* in_sizes, int n_in,
                              void* d_out, int out_size, void* d_ws,
                              size_t ws_size, hipStream_t stream) {
  const float* emb = (const float*)d_in[0];
  const float* keys = (const float*)d_in[1];
  const float* values = (const float*)d_in[2];
  const float* conn = (const float*)d_in[3];
  const float* Wq = (const float*)d_in[4];
  const float* bq = (const float*)d_in[5];
  const float* ln_g = (const float*)d_in[6];
  const float* ln_b = (const float*)d_in[7];
  const float* Wre = (const float*)d_in[8];
  const float* bre = (const float*)d_in[9];
  float* out = (float*)d_out;

  // workspace layout (floats): qT 1M | ln_in 1M | KT 0.5M | VT 0.5M = 12 MB
  float* ws_qT = (float*)d_ws;
  float* ws_ln = ws_qT + 1024 * 1024;
  float* ws_KT = ws_ln + 1024 * 1024;
  float* ws_VT = ws_KT + 64 * 4 * 512 * 4;

  kv_transpose<<<dim3(8, 8), 256, 0, stream>>>(keys, values, ws_KT, ws_VT);
  gemm1024<1><<<dim3(16, 16), 256, 0, stream>>>(emb, Wq, bq, ws_qT);
  attn_kernel<<<dim3(16, 64), 256, 0, stream>>>(ws_qT, ws_KT, ws_VT, conn, ws_ln);
  ln_kernel<<<dim3(1024), 256, 0, stream>>>(ws_ln, ln_g, ln_b);
  gemm1024<0><<<dim3(16, 16), 256, 0, stream>>>(ws_ln, Wre, bre, out);
}

// Round 2
// 168.435 us; speedup vs baseline: 1.7014x; 1.7014x over previous
//
#include <hip/hip_runtime.h>

// Problem constants: B=2,S=512,E=1024; G=4,H=8,Q=16,D=2,V=16,N=512
// bgh = (b*4+g)*8+h in [0,64); sd in [0,1024); n in [0,512)

typedef __attribute__((ext_vector_type(4))) short bf16x4;
typedef __attribute__((ext_vector_type(4))) float f32x4;

static __device__ __forceinline__ unsigned short f2bf(float f) {
  union { float f; unsigned u; } v; v.f = f;
  unsigned r = v.u + 0x7fffu + ((v.u >> 16) & 1u);
  return (unsigned short)(r >> 16);
}

#if defined(__has_builtin)
#if __has_builtin(__builtin_amdgcn_mfma_f32_16x16x16bf16_1k)
#define HAVE_MFMA16 1
#endif
#endif

static __device__ __forceinline__ f32x4 mfma16(bf16x4 a, bf16x4 b, f32x4 c) {
#ifdef HAVE_MFMA16
  return __builtin_amdgcn_mfma_f32_16x16x16bf16_1k(a, b, c, 0, 0, 0);
#else
  f32x4 d;
  asm volatile("v_mfma_f32_16x16x16_bf16 %0, %1, %2, %3\n\t"
               "s_nop 7\n\ts_nop 7"
               : "=&v"(d)
               : "v"(a), "v"(b), "v"(c));
  return d;
#endif
}

// ---------------------------------------------------------------------------
// Kernel 1: transpose keys/values into MFMA-friendly bf16 layouts.
// keys  [B,G,N,Q*H] f32 -> KTb[bgh][n][16 q]  bf16
// values[B,G,N,V*H] f32 -> VTb[bgh][16 v][512 n] bf16
// ---------------------------------------------------------------------------
__global__ __launch_bounds__(256) void kv_transpose(
    const float* __restrict__ keys, const float* __restrict__ values,
    unsigned short* __restrict__ KTb, unsigned short* __restrict__ VTb) {
  const int bg = blockIdx.y;   // 0..7
  const int nb = blockIdx.x;   // 0..7
  const int tid = threadIdx.x;
  const long src_base = (long)bg * 512 * 128 + (long)nb * 64 * 128;
#pragma unroll
  for (int i = 0; i < 8; ++i) {
    int idx = tid + i * 256;            // 0..2047 (64 rows x 32 float4)
    int nl = idx >> 5, c4 = idx & 31;
    int n = nb * 64 + nl;
    float4 kv = *reinterpret_cast<const float4*>(&keys[src_base + nl * 128 + c4 * 4]);
    float4 vv = *reinterpret_cast<const float4*>(&values[src_base + nl * 128 + c4 * 4]);
    float kk[4] = {kv.x, kv.y, kv.z, kv.w};
    float vl[4] = {vv.x, vv.y, vv.z, vv.w};
#pragma unroll
    for (int cc = 0; cc < 4; ++cc) {
      int col = c4 * 4 + cc;            // qq*8 + h
      int h = col & 7, qv = col >> 3;
      int bgh = bg * 8 + h;
      KTb[((long)bgh * 512 + n) * 16 + qv] = f2bf(kk[cc]);
      VTb[((long)bgh * 16 + qv) * 512 + n] = f2bf(vl[cc]);
    }
  }
}

// ---------------------------------------------------------------------------
// Kernel 2/5: f32 GEMM, C[1024,1024] = A @ B + bias (unchanged, passing).
// MODE 0: row-major store (final projection). MODE 1: q-proj scatter to qT.
// ---------------------------------------------------------------------------
template <int MODE>
__global__ __launch_bounds__(256) void gemm1024(
    const float* __restrict__ A, const float* __restrict__ Bm,
    const float* __restrict__ bias, float* __restrict__ C) {
  __shared__ float As[16][64];
  __shared__ float Bs[16][64];
  const int tid = threadIdx.x;
  const int tx = tid & 15, ty = tid >> 4;
  const int brow = blockIdx.y * 64, bcol = blockIdx.x * 64;

  const int arow = tid >> 2;
  const int ak4 = (tid & 3) * 4;
  const int bkrow = tid >> 4;
  const int bcol4 = (tid & 15) * 4;

  float acc[4][4] = {};

  for (int kt = 0; kt < 1024; kt += 16) {
    float4 a4 = *reinterpret_cast<const float4*>(&A[(brow + arow) * 1024 + kt + ak4]);
    float4 b4 = *reinterpret_cast<const float4*>(&Bm[(kt + bkrow) * 1024 + bcol + bcol4]);
    __syncthreads();
    As[ak4 + 0][arow] = a4.x;
    As[ak4 + 1][arow] = a4.y;
    As[ak4 + 2][arow] = a4.z;
    As[ak4 + 3][arow] = a4.w;
    *reinterpret_cast<float4*>(&Bs[bkrow][bcol4]) = b4;
    __syncthreads();
#pragma unroll
    for (int kk = 0; kk < 16; ++kk) {
      float4 av = *reinterpret_cast<const float4*>(&As[kk][ty * 4]);
      float4 bv = *reinterpret_cast<const float4*>(&Bs[kk][tx * 4]);
      float am[4] = {av.x, av.y, av.z, av.w};
      float bm[4] = {bv.x, bv.y, bv.z, bv.w};
#pragma unroll
      for (int i = 0; i < 4; ++i)
#pragma unroll
        for (int j = 0; j < 4; ++j) acc[i][j] += am[i] * bm[j];
    }
  }

  if (MODE == 0) {
#pragma unroll
    for (int i = 0; i < 4; ++i) {
      float4 o;
      o.x = acc[i][0] + bias[bcol + tx * 4 + 0];
      o.y = acc[i][1] + bias[bcol + tx * 4 + 1];
      o.z = acc[i][2] + bias[bcol + tx * 4 + 2];
      o.w = acc[i][3] + bias[bcol + tx * 4 + 3];
      *reinterpret_cast<float4*>(&C[(brow + ty * 4 + i) * 1024 + bcol + tx * 4]) = o;
    }
  } else {
#pragma unroll
    for (int i = 0; i < 4; ++i) {
      int row = brow + ty * 4 + i;
      int b = row >> 9, s = row & 511, g = s >> 7;
#pragma unroll
      for (int j = 0; j < 4; ++j) {
        int colc = bcol + tx * 4 + j;
        float v = acc[i][j] + bias[colc];
        int h = colc & 7, qqi = (colc >> 3) & 15, chi = colc >> 7;
        int sd = (s & 127) * 8 + chi;
        int bgh = b * 32 + g * 8 + h;
        C[((long)bgh * 1024 + sd) * 16 + qqi] = v;
      }
    }
  }
}

// ---------------------------------------------------------------------------
// Kernel 3: MFMA flash attention. Block = 4 waves; wave w owns sd-tile
// [rb*64 + w*16, +16) of one bgh. Swapped-operand scheme:
//   S^T[n][sd] = mfma(A=K[n][q], B=Q^T[q][sd])   (16x16x16 bf16, K=q=16)
//   O^T[v][sd] = mfma(A=V^T[v][n], B=P^T[n][sd]) accumulated over n
// S^T C-layout (n = 4*hi+reg, sd = lane&15) IS the P^T B-frag layout -> the
// softmaxed probabilities feed PV directly, no cross-lane movement.
// conn_sub (the 134 MB HBM stream) is read as float4 straight into registers.
// ---------------------------------------------------------------------------
__global__ __launch_bounds__(256) void attn_mfma(
    const float* __restrict__ qT, const unsigned short* __restrict__ KTb,
    const unsigned short* __restrict__ VTb, const float* __restrict__ conn,
    float* __restrict__ ln_in) {
  __shared__ float O_lds[4][16][17];

  const int tid = threadIdx.x;
  const int wid = tid >> 6, lane = tid & 63;
  const int c = lane & 15, hi = lane >> 4;
  const int rb = blockIdx.x;      // 0..15
  const int bgh = blockIdx.y;     // 0..63
  const int b = bgh >> 5, g = (bgh >> 3) & 3, h = bgh & 7;
  const int sd = rb * 64 + wid * 16 + c;

  // Q fragment: Q[sd][4*hi + i], held in registers for the whole kernel.
  float4 qf = *reinterpret_cast<const float4*>(
      &qT[((long)bgh * 1024 + sd) * 16 + hi * 4]);
  bf16x4 qb;
  qb[0] = (short)f2bf(qf.x);
  qb[1] = (short)f2bf(qf.y);
  qb[2] = (short)f2bf(qf.z);
  qb[3] = (short)f2bf(qf.w);

  const unsigned short* kp = KTb + (long)bgh * 8192 + hi * 4;             // +(n)*16
  const unsigned short* vp = VTb + (long)bgh * 8192 + (long)c * 512 + hi * 4;  // +n
  const float* cp = conn + ((long)bgh * 1024 + sd) * 512 + hi * 4;        // +n0

  f32x4 acc = {0.f, 0.f, 0.f, 0.f};
  float m = -1e30f, lsum = 0.f;

  for (int nb = 0; nb < 512; nb += 64) {
    f32x4 sv[4];
    float cv[16];
    const f32x4 zero = {0.f, 0.f, 0.f, 0.f};
#pragma unroll
    for (int t = 0; t < 4; ++t) {
      const int n0 = nb + t * 16;
      bf16x4 ka = *reinterpret_cast<const bf16x4*>(kp + (long)(n0 + c) * 16);
      float4 cf = *reinterpret_cast<const float4*>(cp + n0);
      sv[t] = mfma16(ka, qb, zero);
      cv[t * 4 + 0] = cf.x;
      cv[t * 4 + 1] = cf.y;
      cv[t * 4 + 2] = cf.z;
      cv[t * 4 + 3] = cf.w;
    }
    float s[16];
#pragma unroll
    for (int t = 0; t < 4; ++t)
#pragma unroll
      for (int r = 0; r < 4; ++r) s[t * 4 + r] = sv[t][r] * 0.25f - cv[t * 4 + r];

    float cmax = s[0];
#pragma unroll
    for (int j = 1; j < 16; ++j) cmax = fmaxf(cmax, s[j]);
    cmax = fmaxf(cmax, __shfl_xor(cmax, 16, 64));
    cmax = fmaxf(cmax, __shfl_xor(cmax, 32, 64));
    const float mnew = fmaxf(m, cmax);
    const float fac = __expf(m - mnew);   // first iter: exp(-huge) = 0
    acc *= fac;
    lsum *= fac;
    float p[16];
    float csum = 0.f;
#pragma unroll
    for (int j = 0; j < 16; ++j) {
      p[j] = __expf(s[j] - mnew);
      csum += p[j];
    }
    lsum += csum;
    m = mnew;
#pragma unroll
    for (int t = 0; t < 4; ++t) {
      const int n0 = nb + t * 16;
      bf16x4 pb;
      pb[0] = (short)f2bf(p[t * 4 + 0]);
      pb[1] = (short)f2bf(p[t * 4 + 1]);
      pb[2] = (short)f2bf(p[t * 4 + 2]);
      pb[3] = (short)f2bf(p[t * 4 + 3]);
      bf16x4 va = *reinterpret_cast<const bf16x4*>(vp + n0);
      acc = mfma16(va, pb, acc);
    }
  }

  lsum += __shfl_xor(lsum, 16, 64);
  lsum += __shfl_xor(lsum, 32, 64);
  const float rinv = 1.0f / lsum;
#pragma unroll
  for (int r = 0; r < 4; ++r) O_lds[wid][c][hi * 4 + r] = acc[r] * rinv;
  __syncthreads();

  // cooperative coalesced write: ch = g*256 + h*32 + dd*16 + v, sd = dd*512+ss
  const int dd = (rb * 64) >> 9;  // uniform within block
  const int chb = g * 256 + h * 32 + dd * 16;
#pragma unroll
  for (int pass = 0; pass < 4; ++pass) {
    int rr = pass * 16 + (tid >> 4);
    int v = tid & 15;
    int ssi = (rb * 64 + rr) & 511;
    ln_in[(long)(b * 512 + ssi) * 1024 + chb + v] = O_lds[rr >> 4][rr & 15][v];
  }
}

// ---------------------------------------------------------------------------
// Kernel 4: in-place LayerNorm over last dim (1024), one block per row.
// ---------------------------------------------------------------------------
__global__ __launch_bounds__(256) void ln_kernel(
    float* __restrict__ x, const float* __restrict__ gamma,
    const float* __restrict__ beta) {
  const int row = blockIdx.x;
  const int tid = threadIdx.x;
  float4 v = *reinterpret_cast<const float4*>(&x[(long)row * 1024 + tid * 4]);
  float s = v.x + v.y + v.z + v.w;
  float s2 = v.x * v.x + v.y * v.y + v.z * v.z + v.w * v.w;
#pragma unroll
  for (int w = 32; w >= 1; w >>= 1) {
    s += __shfl_xor(s, w, 64);
    s2 += __shfl_xor(s2, w, 64);
  }
  __shared__ float red[8];
  const int lane = tid & 63, wid = tid >> 6;
  if (lane == 0) {
    red[wid] = s;
    red[wid + 4] = s2;
  }
  __syncthreads();
  s = red[0] + red[1] + red[2] + red[3];
  s2 = red[4] + red[5] + red[6] + red[7];
  const float mu = s * (1.0f / 1024.0f);
  const float var = s2 * (1.0f / 1024.0f) - mu * mu;
  const float rstd = rsqrtf(var + 1e-5f);
  float4 g4 = *reinterpret_cast<const float4*>(&gamma[tid * 4]);
  float4 b4 = *reinterpret_cast<const float4*>(&beta[tid * 4]);
  float4 o;
  o.x = (v.x - mu) * rstd * g4.x + b4.x;
  o.y = (v.y - mu) * rstd * g4.y + b4.y;
  o.z = (v.z - mu) * rstd * g4.z + b4.z;
  o.w = (v.w - mu) * rstd * g4.w + b4.w;
  *reinterpret_cast<float4*>(&x[(long)row * 1024 + tid * 4]) = o;
}

// ---------------------------------------------------------------------------
extern "C" void kernel_launch(void* const* d_in, const int* in_sizes, int n_in,
                              void* d_out, int out_size, void* d_ws,
                              size_t ws_size, hipStream_t stream) {
  const float* emb = (const float*)d_in[0];
  const float* keys = (const float*)d_in[1];
  const float* values = (const float*)d_in[2];
  const float* conn = (const float*)d_in[3];
  const float* Wq = (const float*)d_in[4];
  const float* bq = (const float*)d_in[5];
  const float* ln_g = (const float*)d_in[6];
  const float* ln_b = (const float*)d_in[7];
  const float* Wre = (const float*)d_in[8];
  const float* bre = (const float*)d_in[9];
  float* out = (float*)d_out;

  // workspace: qT 4MB | ln_in 4MB | KTb 1MB | VTb 1MB
  float* ws_qT = (float*)d_ws;
  float* ws_ln = ws_qT + 1024 * 1024;
  unsigned short* ws_KT = (unsigned short*)(ws_ln + 1024 * 1024);
  unsigned short* ws_VT = ws_KT + 64 * 512 * 16;

  kv_transpose<<<dim3(8, 8), 256, 0, stream>>>(keys, values, ws_KT, ws_VT);
  gemm1024<1><<<dim3(16, 16), 256, 0, stream>>>(emb, Wq, bq, ws_qT);
  attn_mfma<<<dim3(16, 64), 256, 0, stream>>>(ws_qT, ws_KT, ws_VT, conn, ws_ln);
  ln_kernel<<<dim3(1024), 256, 0, stream>>>(ws_ln, ln_g, ln_b);
  gemm1024<0><<<dim3(16, 16), 256, 0, stream>>>(ws_ln, Wre, bre, out);
}

// Round 3
// 89.130 us; speedup vs baseline: 3.2152x; 1.8898x over previous
//
#include <hip/hip_runtime.h>

// Problem constants: B=2,S=512,E=1024; G=4,H=8,Q=16,D=2,V=16,N=512
// bgh = (b*4+g)*8+h in [0,64); sd in [0,1024); n in [0,512)

typedef __attribute__((ext_vector_type(4))) short bf16x4;
typedef __attribute__((ext_vector_type(8))) short short8;
typedef __attribute__((ext_vector_type(8))) unsigned short ushort8;
typedef __attribute__((ext_vector_type(8))) __bf16 bf16x8_t;
typedef __attribute__((ext_vector_type(4))) float f32x4;

static __device__ __forceinline__ unsigned short f2bf(float f) {
  union { float f; unsigned u; } v; v.f = f;
  unsigned r = v.u + 0x7fffu + ((v.u >> 16) & 1u);
  return (unsigned short)(r >> 16);
}

#if defined(__has_builtin)
#if __has_builtin(__builtin_amdgcn_mfma_f32_16x16x16bf16_1k)
#define HAVE_MFMA16 1
#endif
#if __has_builtin(__builtin_amdgcn_mfma_f32_16x16x32_bf16)
#define HAVE_MFMA32 1
#endif
#endif

static __device__ __forceinline__ f32x4 mfma16(bf16x4 a, bf16x4 b, f32x4 c) {
#ifdef HAVE_MFMA16
  return __builtin_amdgcn_mfma_f32_16x16x16bf16_1k(a, b, c, 0, 0, 0);
#else
  f32x4 d;
  asm volatile("v_mfma_f32_16x16x16_bf16 %0, %1, %2, %3\n\t"
               "s_nop 7\n\ts_nop 7"
               : "=&v"(d)
               : "v"(a), "v"(b), "v"(c));
  return d;
#endif
}

#ifdef HAVE_MFMA32
static __device__ __forceinline__ f32x4 mfma32(short8 a, short8 b, f32x4 c) {
  return __builtin_amdgcn_mfma_f32_16x16x32_bf16(
      __builtin_bit_cast(bf16x8_t, a), __builtin_bit_cast(bf16x8_t, b), c, 0, 0, 0);
}
#endif

// ---------------------------------------------------------------------------
// Prep A: convert f32 -> bf16, 1024*1024 elements. grid 512 x 256.
// ---------------------------------------------------------------------------
__global__ __launch_bounds__(256) void cvt_bf16(const float* __restrict__ in,
                                                unsigned short* __restrict__ out) {
  const long i = ((long)blockIdx.x * 256 + threadIdx.x) * 8;
  float4 a = *reinterpret_cast<const float4*>(&in[i]);
  float4 b = *reinterpret_cast<const float4*>(&in[i + 4]);
  ushort8 o;
  o[0] = f2bf(a.x); o[1] = f2bf(a.y); o[2] = f2bf(a.z); o[3] = f2bf(a.w);
  o[4] = f2bf(b.x); o[5] = f2bf(b.y); o[6] = f2bf(b.z); o[7] = f2bf(b.w);
  *reinterpret_cast<ushort8*>(&out[i]) = o;
}

// ---------------------------------------------------------------------------
// Prep W: transpose+convert 1024x1024 f32 W -> bf16 WT[n][k]. grid (16,16).
// ---------------------------------------------------------------------------
__global__ __launch_bounds__(256) void transpose_w(const float* __restrict__ W,
                                                   unsigned short* __restrict__ WT) {
  __shared__ __align__(16) unsigned short t[64][72];  // t[c][r] = W[by+r][bx+c]
  const int bx = blockIdx.x * 64, by = blockIdx.y * 64;
  const int tid = threadIdx.x;
  const int r = tid >> 2;
  const int c0 = (tid & 3) * 16;
#pragma unroll
  for (int j = 0; j < 16; j += 4) {
    float4 v = *reinterpret_cast<const float4*>(&W[(long)(by + r) * 1024 + bx + c0 + j]);
    t[c0 + j + 0][r] = f2bf(v.x);
    t[c0 + j + 1][r] = f2bf(v.y);
    t[c0 + j + 2][r] = f2bf(v.z);
    t[c0 + j + 3][r] = f2bf(v.w);
  }
  __syncthreads();
  // WT[bx + r][by + c] = t[r][c]
#pragma unroll
  for (int j = 0; j < 16; j += 8) {
    *reinterpret_cast<ushort8*>(&WT[(long)(bx + r) * 1024 + by + c0 + j]) =
        *reinterpret_cast<const ushort8*>(&t[r][c0 + j]);
  }
}

// ---------------------------------------------------------------------------
// KV transpose: keys [B,G,N,Q*H] f32 -> KTb[bgh][n][16 q] bf16
//               values[B,G,N,V*H] f32 -> VTb[bgh][16 v][512 n] bf16
// ---------------------------------------------------------------------------
__global__ __launch_bounds__(256) void kv_transpose(
    const float* __restrict__ keys, const float* __restrict__ values,
    unsigned short* __restrict__ KTb, unsigned short* __restrict__ VTb) {
  const int bg = blockIdx.y;
  const int nb = blockIdx.x;
  const int tid = threadIdx.x;
  const long src_base = (long)bg * 512 * 128 + (long)nb * 64 * 128;
#pragma unroll
  for (int i = 0; i < 8; ++i) {
    int idx = tid + i * 256;
    int nl = idx >> 5, c4 = idx & 31;
    int n = nb * 64 + nl;
    float4 kv = *reinterpret_cast<const float4*>(&keys[src_base + nl * 128 + c4 * 4]);
    float4 vv = *reinterpret_cast<const float4*>(&values[src_base + nl * 128 + c4 * 4]);
    float kk[4] = {kv.x, kv.y, kv.z, kv.w};
    float vl[4] = {vv.x, vv.y, vv.z, vv.w};
#pragma unroll
    for (int cc = 0; cc < 4; ++cc) {
      int col = c4 * 4 + cc;            // qq*8 + h
      int h = col & 7, qv = col >> 3;
      int bgh = bg * 8 + h;
      KTb[((long)bgh * 512 + n) * 16 + qv] = f2bf(kk[cc]);
      VTb[((long)bgh * 16 + qv) * 512 + n] = f2bf(vl[cc]);
    }
  }
}

// ---------------------------------------------------------------------------
// bf16 MFMA GEMM: C[1024,1024] = A[m][k] @ BT[n][k]^T + bias.
// Tile 64x64, BK=32, 512 threads = 8 waves as 2(M) x 4(N), wave tile 32x16.
// LDS K-major [64][40] (pad -> 2-way bank alias only), double-buffered.
// MODE 0: f32 row-major store (final proj). MODE 1: bf16 scatter to qT.
// ---------------------------------------------------------------------------
template <int MODE>
__global__ __launch_bounds__(512) void gemm_bf16(
    const unsigned short* __restrict__ A, const unsigned short* __restrict__ BT,
    const float* __restrict__ bias, void* __restrict__ Cout) {
  __shared__ __align__(16) unsigned short As[2][64][40];
  __shared__ __align__(16) unsigned short Bs[2][64][40];
  const int tid = threadIdx.x;
  const int brow = blockIdx.y * 64, bcol = blockIdx.x * 64;
  const int lane = tid & 63, w = tid >> 6;
  const int wr = w >> 2, wc = w & 3;
  const int fr = lane & 15, kg = lane >> 4;   // frag row / k-group

  // staging: threads 0-255 stage A (64x32), 256-511 stage B (64x32)
  const int sIsB = tid >= 256;
  const int st = tid & 255;
  const int srow = st >> 2, sc0 = (st & 3) * 8;
  const unsigned short* sp = sIsB ? (BT + (long)(bcol + srow) * 1024 + sc0)
                                  : (A + (long)(brow + srow) * 1024 + sc0);

  f32x4 acc[2] = {{0.f, 0.f, 0.f, 0.f}, {0.f, 0.f, 0.f, 0.f}};

  ushort8 stg = *reinterpret_cast<const ushort8*>(sp);
  int buf = 0;
  for (int kt = 0; kt < 1024; kt += 32) {
    unsigned short* dst = sIsB ? &Bs[buf][srow][sc0] : &As[buf][srow][sc0];
    *reinterpret_cast<ushort8*>(dst) = stg;
    __syncthreads();
    if (kt + 32 < 1024) stg = *reinterpret_cast<const ushort8*>(sp + kt + 32);
#ifdef HAVE_MFMA32
    short8 bfrag = *reinterpret_cast<const short8*>(&Bs[buf][wc * 16 + fr][kg * 8]);
    short8 a0 = *reinterpret_cast<const short8*>(&As[buf][wr * 32 + fr][kg * 8]);
    short8 a1 = *reinterpret_cast<const short8*>(&As[buf][wr * 32 + 16 + fr][kg * 8]);
    acc[0] = mfma32(a0, bfrag, acc[0]);
    acc[1] = mfma32(a1, bfrag, acc[1]);
#else
    // fallback: two 16x16x16 steps (k = kg*4 + [0,4) and 16 + kg*4 + [0,4))
    bf16x4 blo = *reinterpret_cast<const bf16x4*>(&Bs[buf][wc * 16 + fr][kg * 4]);
    bf16x4 bhi = *reinterpret_cast<const bf16x4*>(&Bs[buf][wc * 16 + fr][16 + kg * 4]);
#pragma unroll
    for (int m = 0; m < 2; ++m) {
      bf16x4 alo = *reinterpret_cast<const bf16x4*>(&As[buf][wr * 32 + m * 16 + fr][kg * 4]);
      bf16x4 ahi = *reinterpret_cast<const bf16x4*>(&As[buf][wr * 32 + m * 16 + fr][16 + kg * 4]);
      acc[m] = mfma16(alo, blo, acc[m]);
      acc[m] = mfma16(ahi, bhi, acc[m]);
    }
#endif
    buf ^= 1;
  }

  const int colc = bcol + wc * 16 + fr;
  const float bv = bias[colc];
  if (MODE == 0) {
    float* C = (float*)Cout;
#pragma unroll
    for (int m = 0; m < 2; ++m)
#pragma unroll
      for (int j = 0; j < 4; ++j) {
        int row = brow + wr * 32 + m * 16 + kg * 4 + j;
        C[(long)row * 1024 + colc] = acc[m][j] + bv;
      }
  } else {
    unsigned short* C = (unsigned short*)Cout;
    const int h = colc & 7, qqi = (colc >> 3) & 15, chi = colc >> 7;
#pragma unroll
    for (int m = 0; m < 2; ++m)
#pragma unroll
      for (int j = 0; j < 4; ++j) {
        int row = brow + wr * 32 + m * 16 + kg * 4 + j;
        int b = row >> 9, s = row & 511, g = s >> 7;
        int sd = (s & 127) * 8 + chi;
        int bgh = b * 32 + g * 8 + h;
        C[((long)bgh * 1024 + sd) * 16 + qqi] = f2bf(acc[m][j] + bv);
      }
  }
}

// ---------------------------------------------------------------------------
// MFMA flash attention (unchanged logic; Q now read directly as bf16).
//   S^T[n][sd] = mfma(A=K[n][q], B=Q^T[q][sd]); online softmax;
//   O^T[v][sd] = mfma(A=V^T[v][n], B=P^T[n][sd]).
// ---------------------------------------------------------------------------
__global__ __launch_bounds__(256) void attn_mfma(
    const unsigned short* __restrict__ qTb, const unsigned short* __restrict__ KTb,
    const unsigned short* __restrict__ VTb, const float* __restrict__ conn,
    float* __restrict__ ln_in) {
  __shared__ float O_lds[4][16][17];

  const int tid = threadIdx.x;
  const int wid = tid >> 6, lane = tid & 63;
  const int c = lane & 15, hi = lane >> 4;
  const int rb = blockIdx.x;
  const int bgh = blockIdx.y;
  const int b = bgh >> 5, g = (bgh >> 3) & 3, h = bgh & 7;
  const int sd = rb * 64 + wid * 16 + c;

  bf16x4 qb = *reinterpret_cast<const bf16x4*>(&qTb[((long)bgh * 1024 + sd) * 16 + hi * 4]);

  const unsigned short* kp = KTb + (long)bgh * 8192 + hi * 4;
  const unsigned short* vp = VTb + (long)bgh * 8192 + (long)c * 512 + hi * 4;
  const float* cp = conn + ((long)bgh * 1024 + sd) * 512 + hi * 4;

  f32x4 acc = {0.f, 0.f, 0.f, 0.f};
  float m = -1e30f, lsum = 0.f;

  for (int nb = 0; nb < 512; nb += 64) {
    f32x4 sv[4];
    float cv[16];
    const f32x4 zero = {0.f, 0.f, 0.f, 0.f};
#pragma unroll
    for (int t = 0; t < 4; ++t) {
      const int n0 = nb + t * 16;
      bf16x4 ka = *reinterpret_cast<const bf16x4*>(kp + (long)(n0 + c) * 16);
      float4 cf = *reinterpret_cast<const float4*>(cp + n0);
      sv[t] = mfma16(ka, qb, zero);
      cv[t * 4 + 0] = cf.x;
      cv[t * 4 + 1] = cf.y;
      cv[t * 4 + 2] = cf.z;
      cv[t * 4 + 3] = cf.w;
    }
    float s[16];
#pragma unroll
    for (int t = 0; t < 4; ++t)
#pragma unroll
      for (int r = 0; r < 4; ++r) s[t * 4 + r] = sv[t][r] * 0.25f - cv[t * 4 + r];

    float cmax = s[0];
#pragma unroll
    for (int j = 1; j < 16; ++j) cmax = fmaxf(cmax, s[j]);
    cmax = fmaxf(cmax, __shfl_xor(cmax, 16, 64));
    cmax = fmaxf(cmax, __shfl_xor(cmax, 32, 64));
    const float mnew = fmaxf(m, cmax);
    const float fac = __expf(m - mnew);
    acc *= fac;
    lsum *= fac;
    float p[16];
    float csum = 0.f;
#pragma unroll
    for (int j = 0; j < 16; ++j) {
      p[j] = __expf(s[j] - mnew);
      csum += p[j];
    }
    lsum += csum;
    m = mnew;
#pragma unroll
    for (int t = 0; t < 4; ++t) {
      const int n0 = nb + t * 16;
      bf16x4 pb;
      pb[0] = (short)f2bf(p[t * 4 + 0]);
      pb[1] = (short)f2bf(p[t * 4 + 1]);
      pb[2] = (short)f2bf(p[t * 4 + 2]);
      pb[3] = (short)f2bf(p[t * 4 + 3]);
      bf16x4 va = *reinterpret_cast<const bf16x4*>(vp + n0);
      acc = mfma16(va, pb, acc);
    }
  }

  lsum += __shfl_xor(lsum, 16, 64);
  lsum += __shfl_xor(lsum, 32, 64);
  const float rinv = 1.0f / lsum;
#pragma unroll
  for (int r = 0; r < 4; ++r) O_lds[wid][c][hi * 4 + r] = acc[r] * rinv;
  __syncthreads();

  const int dd = (rb * 64) >> 9;
  const int chb = g * 256 + h * 32 + dd * 16;
#pragma unroll
  for (int pass = 0; pass < 4; ++pass) {
    int rr = pass * 16 + (tid >> 4);
    int v = tid & 15;
    int ssi = (rb * 64 + rr) & 511;
    ln_in[(long)(b * 512 + ssi) * 1024 + chb + v] = O_lds[rr >> 4][rr & 15][v];
  }
}

// ---------------------------------------------------------------------------
// LayerNorm over last dim (1024); reads f32, writes bf16 (A of final GEMM).
// ---------------------------------------------------------------------------
__global__ __launch_bounds__(256) void ln_kernel(
    const float* __restrict__ x, const float* __restrict__ gamma,
    const float* __restrict__ beta, unsigned short* __restrict__ out) {
  const int row = blockIdx.x;
  const int tid = threadIdx.x;
  float4 v = *reinterpret_cast<const float4*>(&x[(long)row * 1024 + tid * 4]);
  float s = v.x + v.y + v.z + v.w;
  float s2 = v.x * v.x + v.y * v.y + v.z * v.z + v.w * v.w;
#pragma unroll
  for (int w = 32; w >= 1; w >>= 1) {
    s += __shfl_xor(s, w, 64);
    s2 += __shfl_xor(s2, w, 64);
  }
  __shared__ float red[8];
  const int lane = tid & 63, wid = tid >> 6;
  if (lane == 0) {
    red[wid] = s;
    red[wid + 4] = s2;
  }
  __syncthreads();
  s = red[0] + red[1] + red[2] + red[3];
  s2 = red[4] + red[5] + red[6] + red[7];
  const float mu = s * (1.0f / 1024.0f);
  const float var = s2 * (1.0f / 1024.0f) - mu * mu;
  const float rstd = rsqrtf(var + 1e-5f);
  float4 g4 = *reinterpret_cast<const float4*>(&gamma[tid * 4]);
  float4 b4 = *reinterpret_cast<const float4*>(&beta[tid * 4]);
  unsigned short o[4];
  o[0] = f2bf((v.x - mu) * rstd * g4.x + b4.x);
  o[1] = f2bf((v.y - mu) * rstd * g4.y + b4.y);
  o[2] = f2bf((v.z - mu) * rstd * g4.z + b4.z);
  o[3] = f2bf((v.w - mu) * rstd * g4.w + b4.w);
  *reinterpret_cast<uint2*>(&out[(long)row * 1024 + tid * 4]) = *reinterpret_cast<uint2*>(o);
}

// ---------------------------------------------------------------------------
extern "C" void kernel_launch(void* const* d_in, const int* in_sizes, int n_in,
                              void* d_out, int out_size, void* d_ws,
                              size_t ws_size, hipStream_t stream) {
  const float* emb = (const float*)d_in[0];
  const float* keys = (const float*)d_in[1];
  const float* values = (const float*)d_in[2];
  const float* conn = (const float*)d_in[3];
  const float* Wq = (const float*)d_in[4];
  const float* bq = (const float*)d_in[5];
  const float* ln_g = (const float*)d_in[6];
  const float* ln_b = (const float*)d_in[7];
  const float* Wre = (const float*)d_in[8];
  const float* bre = (const float*)d_in[9];
  float* out = (float*)d_out;

  // workspace (14 MB):
  char* w = (char*)d_ws;
  float* ws_ln = (float*)w;                                       // 4 MB
  unsigned short* ws_Ab = (unsigned short*)(w + 4 * 1024 * 1024); // 2 MB (emb bf16, later ln bf16)
  unsigned short* ws_WqT = (unsigned short*)(w + 6 * 1024 * 1024);  // 2 MB
  unsigned short* ws_WreT = (unsigned short*)(w + 8 * 1024 * 1024); // 2 MB
  unsigned short* ws_qTb = (unsigned short*)(w + 10 * 1024 * 1024); // 2 MB
  unsigned short* ws_KTb = (unsigned short*)(w + 12 * 1024 * 1024); // 1 MB
  unsigned short* ws_VTb = (unsigned short*)(w + 13 * 1024 * 1024); // 1 MB

  cvt_bf16<<<512, 256, 0, stream>>>(emb, ws_Ab);
  transpose_w<<<dim3(16, 16), 256, 0, stream>>>(Wq, ws_WqT);
  transpose_w<<<dim3(16, 16), 256, 0, stream>>>(Wre, ws_WreT);
  kv_transpose<<<dim3(8, 8), 256, 0, stream>>>(keys, values, ws_KTb, ws_VTb);
  gemm_bf16<1><<<dim3(16, 16), 512, 0, stream>>>(ws_Ab, ws_WqT, bq, ws_qTb);
  attn_mfma<<<dim3(16, 64), 256, 0, stream>>>(ws_qTb, ws_KTb, ws_VTb, conn, ws_ln);
  ln_kernel<<<1024, 256, 0, stream>>>(ws_ln, ln_g, ln_b, ws_Ab);
  gemm_bf16<0><<<dim3(16, 16), 512, 0, stream>>>(ws_Ab, ws_WreT, bre, out);
}

// Round 4
// 88.377 us; speedup vs baseline: 3.2426x; 1.0085x over previous
//
#include <hip/hip_runtime.h>

// Problem constants: B=2,S=512,E=1024; G=4,H=8,Q=16,D=2,V=16,N=512
// bgh = (b*4+g)*8+h in [0,64); sd in [0,1024); n in [0,512)

typedef __attribute__((ext_vector_type(4))) short bf16x4;
typedef __attribute__((ext_vector_type(8))) short short8;
typedef __attribute__((ext_vector_type(8))) unsigned short ushort8;
typedef __attribute__((ext_vector_type(8))) __bf16 bf16x8_t;
typedef __attribute__((ext_vector_type(4))) float f32x4;

static __device__ __forceinline__ unsigned short f2bf(float f) {
  union { float f; unsigned u; } v; v.f = f;
  unsigned r = v.u + 0x7fffu + ((v.u >> 16) & 1u);
  return (unsigned short)(r >> 16);
}

#if defined(__has_builtin)
#if __has_builtin(__builtin_amdgcn_mfma_f32_16x16x16bf16_1k)
#define HAVE_MFMA16 1
#endif
#if __has_builtin(__builtin_amdgcn_mfma_f32_16x16x32_bf16)
#define HAVE_MFMA32 1
#endif
#endif

static __device__ __forceinline__ f32x4 mfma16(bf16x4 a, bf16x4 b, f32x4 c) {
#ifdef HAVE_MFMA16
  return __builtin_amdgcn_mfma_f32_16x16x16bf16_1k(a, b, c, 0, 0, 0);
#else
  f32x4 d;
  asm volatile("v_mfma_f32_16x16x16_bf16 %0, %1, %2, %3\n\t"
               "s_nop 7\n\ts_nop 7"
               : "=&v"(d)
               : "v"(a), "v"(b), "v"(c));
  return d;
#endif
}

#ifdef HAVE_MFMA32
static __device__ __forceinline__ f32x4 mfma32(short8 a, short8 b, f32x4 c) {
  return __builtin_amdgcn_mfma_f32_16x16x32_bf16(
      __builtin_bit_cast(bf16x8_t, a), __builtin_bit_cast(bf16x8_t, b), c, 0, 0, 0);
}
#endif

// ---------------------------------------------------------------------------
// Prep (single launch, 576 blocks):
//   blocks [0,256)   : Wq  f32 -> WqT[n][k] bf16   (64x64 tile transpose)
//   blocks [256,512) : Wre f32 -> WreT[n][k] bf16
//   blocks [512,576) : keys/values -> KTb[bgh][n][16q], VTb[bgh][16v][512n]
// ---------------------------------------------------------------------------
__global__ __launch_bounds__(256) void prep_all(
    const float* __restrict__ Wq, const float* __restrict__ Wre,
    const float* __restrict__ keys, const float* __restrict__ values,
    unsigned short* __restrict__ WqT, unsigned short* __restrict__ WreT,
    unsigned short* __restrict__ KTb, unsigned short* __restrict__ VTb) {
  __shared__ __align__(16) unsigned short t[64][72];
  const int blk = blockIdx.x;
  const int tid = threadIdx.x;

  if (blk < 512) {
    const float* W = (blk < 256) ? Wq : Wre;
    unsigned short* WT = (blk < 256) ? WqT : WreT;
    const int idx = blk & 255;
    const int bx = (idx & 15) * 64, by = (idx >> 4) * 64;
    const int r = tid >> 2;
    const int c0 = (tid & 3) * 16;
#pragma unroll
    for (int j = 0; j < 16; j += 4) {
      float4 v = *reinterpret_cast<const float4*>(&W[(long)(by + r) * 1024 + bx + c0 + j]);
      t[c0 + j + 0][r] = f2bf(v.x);
      t[c0 + j + 1][r] = f2bf(v.y);
      t[c0 + j + 2][r] = f2bf(v.z);
      t[c0 + j + 3][r] = f2bf(v.w);
    }
    __syncthreads();
#pragma unroll
    for (int j = 0; j < 16; j += 8) {
      *reinterpret_cast<ushort8*>(&WT[(long)(bx + r) * 1024 + by + c0 + j]) =
          *reinterpret_cast<const ushort8*>(&t[r][c0 + j]);
    }
  } else {
    const int kvIdx = blk - 512;
    const int bg = kvIdx >> 3, nb = kvIdx & 7;
    const long src_base = (long)bg * 512 * 128 + (long)nb * 64 * 128;
#pragma unroll
    for (int i = 0; i < 8; ++i) {
      int idx = tid + i * 256;
      int nl = idx >> 5, c4 = idx & 31;
      int n = nb * 64 + nl;
      float4 kv = *reinterpret_cast<const float4*>(&keys[src_base + nl * 128 + c4 * 4]);
      float4 vv = *reinterpret_cast<const float4*>(&values[src_base + nl * 128 + c4 * 4]);
      float kk[4] = {kv.x, kv.y, kv.z, kv.w};
      float vl[4] = {vv.x, vv.y, vv.z, vv.w};
#pragma unroll
      for (int cc = 0; cc < 4; ++cc) {
        int col = c4 * 4 + cc;          // qq*8 + h
        int h = col & 7, qv = col >> 3;
        int bgh = bg * 8 + h;
        KTb[((long)bgh * 512 + n) * 16 + qv] = f2bf(kk[cc]);
        VTb[((long)bgh * 16 + qv) * 512 + n] = f2bf(vl[cc]);
      }
    }
  }
}

// ---------------------------------------------------------------------------
// bf16 MFMA GEMM: C[1024,1024] = A[m][k] @ BT[n][k]^T + bias.
// Tile 64x64, BK=32, 256 threads = 4 waves as 2(M) x 2(N), wave tile 32x32.
// Per K-step per wave: 4 mfma32 on 4 ds_read_b128 (1:1 ratio).
// LDS K-major [64][40] (pad -> 2-way bank alias, free), double-buffered.
// MODE 1: A is f32 (emb), converted during staging; bf16 scatter-store to qT.
// MODE 0: A is bf16 (ln out); f32 row-major store + bias (final output).
// ---------------------------------------------------------------------------
template <int MODE>
__global__ __launch_bounds__(256) void gemm_bf16(
    const void* __restrict__ Ain, const unsigned short* __restrict__ BT,
    const float* __restrict__ bias, void* __restrict__ Cout) {
  __shared__ __align__(16) unsigned short As[2][64][40];
  __shared__ __align__(16) unsigned short Bs[2][64][40];
  const int tid = threadIdx.x;
  const int brow = blockIdx.y * 64, bcol = blockIdx.x * 64;
  const int lane = tid & 63, w = tid >> 6;
  const int wr = w >> 1, wc = w & 1;
  const int fr = lane & 15, kg = lane >> 4;   // frag row / k-group of 8

  // staging indices: each thread loads 8 k-elements of one A row and one B row
  const int srow = tid >> 2, sc0 = (tid & 3) * 8;
  const unsigned short* bp = BT + (long)(bcol + srow) * 1024 + sc0;

  f32x4 acc[2][2] = {{{0.f, 0.f, 0.f, 0.f}, {0.f, 0.f, 0.f, 0.f}},
                     {{0.f, 0.f, 0.f, 0.f}, {0.f, 0.f, 0.f, 0.f}}};

  auto loadA = [&](int kt) -> ushort8 {
    if (MODE == 1) {
      const float* ap = (const float*)Ain + (long)(brow + srow) * 1024 + kt + sc0;
      float4 f0 = *reinterpret_cast<const float4*>(ap);
      float4 f1 = *reinterpret_cast<const float4*>(ap + 4);
      ushort8 o;
      o[0] = f2bf(f0.x); o[1] = f2bf(f0.y); o[2] = f2bf(f0.z); o[3] = f2bf(f0.w);
      o[4] = f2bf(f1.x); o[5] = f2bf(f1.y); o[6] = f2bf(f1.z); o[7] = f2bf(f1.w);
      return o;
    } else {
      return *reinterpret_cast<const ushort8*>(
          (const unsigned short*)Ain + (long)(brow + srow) * 1024 + kt + sc0);
    }
  };

  ushort8 sa = loadA(0);
  ushort8 sb = *reinterpret_cast<const ushort8*>(bp);
  int buf = 0;
  for (int kt = 0; kt < 1024; kt += 32) {
    *reinterpret_cast<ushort8*>(&As[buf][srow][sc0]) = sa;
    *reinterpret_cast<ushort8*>(&Bs[buf][srow][sc0]) = sb;
    __syncthreads();
    if (kt + 32 < 1024) {
      sa = loadA(kt + 32);
      sb = *reinterpret_cast<const ushort8*>(bp + kt + 32);
    }
#ifdef HAVE_MFMA32
    short8 a0 = *reinterpret_cast<const short8*>(&As[buf][wr * 32 + fr][kg * 8]);
    short8 a1 = *reinterpret_cast<const short8*>(&As[buf][wr * 32 + 16 + fr][kg * 8]);
    short8 b0 = *reinterpret_cast<const short8*>(&Bs[buf][wc * 32 + fr][kg * 8]);
    short8 b1 = *reinterpret_cast<const short8*>(&Bs[buf][wc * 32 + 16 + fr][kg * 8]);
    acc[0][0] = mfma32(a0, b0, acc[0][0]);
    acc[0][1] = mfma32(a0, b1, acc[0][1]);
    acc[1][0] = mfma32(a1, b0, acc[1][0]);
    acc[1][1] = mfma32(a1, b1, acc[1][1]);
#else
#pragma unroll
    for (int m = 0; m < 2; ++m) {
      bf16x4 alo = *reinterpret_cast<const bf16x4*>(&As[buf][wr * 32 + m * 16 + fr][kg * 4]);
      bf16x4 ahi = *reinterpret_cast<const bf16x4*>(&As[buf][wr * 32 + m * 16 + fr][16 + kg * 4]);
#pragma unroll
      for (int n = 0; n < 2; ++n) {
        bf16x4 blo = *reinterpret_cast<const bf16x4*>(&Bs[buf][wc * 32 + n * 16 + fr][kg * 4]);
        bf16x4 bhi = *reinterpret_cast<const bf16x4*>(&Bs[buf][wc * 32 + n * 16 + fr][16 + kg * 4]);
        acc[m][n] = mfma16(alo, blo, acc[m][n]);
        acc[m][n] = mfma16(ahi, bhi, acc[m][n]);
      }
    }
#endif
    buf ^= 1;
  }

  if (MODE == 0) {
    float* C = (float*)Cout;
#pragma unroll
    for (int n = 0; n < 2; ++n) {
      const int colc = bcol + wc * 32 + n * 16 + fr;
      const float bv = bias[colc];
#pragma unroll
      for (int m = 0; m < 2; ++m)
#pragma unroll
        for (int j = 0; j < 4; ++j) {
          int row = brow + wr * 32 + m * 16 + kg * 4 + j;
          C[(long)row * 1024 + colc] = acc[m][n][j] + bv;
        }
    }
  } else {
    unsigned short* C = (unsigned short*)Cout;
#pragma unroll
    for (int n = 0; n < 2; ++n) {
      const int colc = bcol + wc * 32 + n * 16 + fr;
      const float bv = bias[colc];
      const int h = colc & 7, qqi = (colc >> 3) & 15, chi = colc >> 7;
#pragma unroll
      for (int m = 0; m < 2; ++m)
#pragma unroll
        for (int j = 0; j < 4; ++j) {
          int row = brow + wr * 32 + m * 16 + kg * 4 + j;
          int b = row >> 9, s = row & 511, g = s >> 7;
          int sd = (s & 127) * 8 + chi;
          int bgh = b * 32 + g * 8 + h;
          C[((long)bgh * 1024 + sd) * 16 + qqi] = f2bf(acc[m][n][j] + bv);
        }
    }
  }
}

// ---------------------------------------------------------------------------
// MFMA flash attention. Block = 4 waves; wave w owns sd-tile
// [rb*64 + w*16, +16) of one bgh. Swapped-operand scheme:
//   S^T[n][sd] = mfma(A=K[n][q], B=Q^T[q][sd]); online softmax (column-local);
//   O^T[v][sd] = mfma(A=V^T[v][n], B=P^T[n][sd])  — S^T C-layout == P^T B-layout.
// conn_sub (134 MB, the HBM stream) read as float4 straight to registers.
// ---------------------------------------------------------------------------
__global__ __launch_bounds__(256) void attn_mfma(
    const unsigned short* __restrict__ qTb, const unsigned short* __restrict__ KTb,
    const unsigned short* __restrict__ VTb, const float* __restrict__ conn,
    float* __restrict__ ln_in) {
  __shared__ float O_lds[4][16][17];

  const int tid = threadIdx.x;
  const int wid = tid >> 6, lane = tid & 63;
  const int c = lane & 15, hi = lane >> 4;
  const int rb = blockIdx.x;
  const int bgh = blockIdx.y;
  const int b = bgh >> 5, g = (bgh >> 3) & 3, h = bgh & 7;
  const int sd = rb * 64 + wid * 16 + c;

  bf16x4 qb = *reinterpret_cast<const bf16x4*>(&qTb[((long)bgh * 1024 + sd) * 16 + hi * 4]);

  const unsigned short* kp = KTb + (long)bgh * 8192 + hi * 4;
  const unsigned short* vp = VTb + (long)bgh * 8192 + (long)c * 512 + hi * 4;
  const float* cp = conn + ((long)bgh * 1024 + sd) * 512 + hi * 4;

  f32x4 acc = {0.f, 0.f, 0.f, 0.f};
  float m = -1e30f, lsum = 0.f;

  for (int nb = 0; nb < 512; nb += 64) {
    f32x4 sv[4];
    float cv[16];
    const f32x4 zero = {0.f, 0.f, 0.f, 0.f};
#pragma unroll
    for (int t = 0; t < 4; ++t) {
      const int n0 = nb + t * 16;
      bf16x4 ka = *reinterpret_cast<const bf16x4*>(kp + (long)(n0 + c) * 16);
      float4 cf = *reinterpret_cast<const float4*>(cp + n0);
      sv[t] = mfma16(ka, qb, zero);
      cv[t * 4 + 0] = cf.x;
      cv[t * 4 + 1] = cf.y;
      cv[t * 4 + 2] = cf.z;
      cv[t * 4 + 3] = cf.w;
    }
    float s[16];
#pragma unroll
    for (int t = 0; t < 4; ++t)
#pragma unroll
      for (int r = 0; r < 4; ++r) s[t * 4 + r] = sv[t][r] * 0.25f - cv[t * 4 + r];

    float cmax = s[0];
#pragma unroll
    for (int j = 1; j < 16; ++j) cmax = fmaxf(cmax, s[j]);
    cmax = fmaxf(cmax, __shfl_xor(cmax, 16, 64));
    cmax = fmaxf(cmax, __shfl_xor(cmax, 32, 64));
    const float mnew = fmaxf(m, cmax);
    const float fac = __expf(m - mnew);
    acc *= fac;
    lsum *= fac;
    float p[16];
    float csum = 0.f;
#pragma unroll
    for (int j = 0; j < 16; ++j) {
      p[j] = __expf(s[j] - mnew);
      csum += p[j];
    }
    lsum += csum;
    m = mnew;
#pragma unroll
    for (int t = 0; t < 4; ++t) {
      const int n0 = nb + t * 16;
      bf16x4 pb;
      pb[0] = (short)f2bf(p[t * 4 + 0]);
      pb[1] = (short)f2bf(p[t * 4 + 1]);
      pb[2] = (short)f2bf(p[t * 4 + 2]);
      pb[3] = (short)f2bf(p[t * 4 + 3]);
      bf16x4 va = *reinterpret_cast<const bf16x4*>(vp + n0);
      acc = mfma16(va, pb, acc);
    }
  }

  lsum += __shfl_xor(lsum, 16, 64);
  lsum += __shfl_xor(lsum, 32, 64);
  const float rinv = 1.0f / lsum;
#pragma unroll
  for (int r = 0; r < 4; ++r) O_lds[wid][c][hi * 4 + r] = acc[r] * rinv;
  __syncthreads();

  const int dd = (rb * 64) >> 9;
  const int chb = g * 256 + h * 32 + dd * 16;
#pragma unroll
  for (int pass = 0; pass < 4; ++pass) {
    int rr = pass * 16 + (tid >> 4);
    int v = tid & 15;
    int ssi = (rb * 64 + rr) & 511;
    ln_in[(long)(b * 512 + ssi) * 1024 + chb + v] = O_lds[rr >> 4][rr & 15][v];
  }
}

// ---------------------------------------------------------------------------
// LayerNorm over last dim (1024); reads f32, writes bf16 (A of final GEMM).
// ---------------------------------------------------------------------------
__global__ __launch_bounds__(256) void ln_kernel(
    const float* __restrict__ x, const float* __restrict__ gamma,
    const float* __restrict__ beta, unsigned short* __restrict__ out) {
  const int row = blockIdx.x;
  const int tid = threadIdx.x;
  float4 v = *reinterpret_cast<const float4*>(&x[(long)row * 1024 + tid * 4]);
  float s = v.x + v.y + v.z + v.w;
  float s2 = v.x * v.x + v.y * v.y + v.z * v.z + v.w * v.w;
#pragma unroll
  for (int w = 32; w >= 1; w >>= 1) {
    s += __shfl_xor(s, w, 64);
    s2 += __shfl_xor(s2, w, 64);
  }
  __shared__ float red[8];
  const int lane = tid & 63, wid = tid >> 6;
  if (lane == 0) {
    red[wid] = s;
    red[wid + 4] = s2;
  }
  __syncthreads();
  s = red[0] + red[1] + red[2] + red[3];
  s2 = red[4] + red[5] + red[6] + red[7];
  const float mu = s * (1.0f / 1024.0f);
  const float var = s2 * (1.0f / 1024.0f) - mu * mu;
  const float rstd = rsqrtf(var + 1e-5f);
  float4 g4 = *reinterpret_cast<const float4*>(&gamma[tid * 4]);
  float4 b4 = *reinterpret_cast<const float4*>(&beta[tid * 4]);
  unsigned short o[4];
  o[0] = f2bf((v.x - mu) * rstd * g4.x + b4.x);
  o[1] = f2bf((v.y - mu) * rstd * g4.y + b4.y);
  o[2] = f2bf((v.z - mu) * rstd * g4.z + b4.z);
  o[3] = f2bf((v.w - mu) * rstd * g4.w + b4.w);
  *reinterpret_cast<uint2*>(&out[(long)row * 1024 + tid * 4]) = *reinterpret_cast<uint2*>(o);
}

// ---------------------------------------------------------------------------
extern "C" void kernel_launch(void* const* d_in, const int* in_sizes, int n_in,
                              void* d_out, int out_size, void* d_ws,
                              size_t ws_size, hipStream_t stream) {
  const float* emb = (const float*)d_in[0];
  const float* keys = (const float*)d_in[1];
  const float* values = (const float*)d_in[2];
  const float* conn = (const float*)d_in[3];
  const float* Wq = (const float*)d_in[4];
  const float* bq = (const float*)d_in[5];
  const float* ln_g = (const float*)d_in[6];
  const float* ln_b = (const float*)d_in[7];
  const float* Wre = (const float*)d_in[8];
  const float* bre = (const float*)d_in[9];
  float* out = (float*)d_out;

  // workspace (14 MB):
  char* w = (char*)d_ws;
  float* ws_ln = (float*)w;                                         // 4 MB
  unsigned short* ws_Ab = (unsigned short*)(w + 4 * 1024 * 1024);   // 2 MB (ln bf16)
  unsigned short* ws_WqT = (unsigned short*)(w + 6 * 1024 * 1024);  // 2 MB
  unsigned short* ws_WreT = (unsigned short*)(w + 8 * 1024 * 1024); // 2 MB
  unsigned short* ws_qTb = (unsigned short*)(w + 10 * 1024 * 1024); // 2 MB
  unsigned short* ws_KTb = (unsigned short*)(w + 12 * 1024 * 1024); // 1 MB
  unsigned short* ws_VTb = (unsigned short*)(w + 13 * 1024 * 1024); // 1 MB

  prep_all<<<576, 256, 0, stream>>>(Wq, Wre, keys, values, ws_WqT, ws_WreT,
                                    ws_KTb, ws_VTb);
  gemm_bf16<1><<<dim3(16, 16), 256, 0, stream>>>(emb, ws_WqT, bq, ws_qTb);
  attn_mfma<<<dim3(16, 64), 256, 0, stream>>>(ws_qTb, ws_KTb, ws_VTb, conn, ws_ln);
  ln_kernel<<<1024, 256, 0, stream>>>(ws_ln, ln_g, ln_b, ws_Ab);
  gemm_bf16<0><<<dim3(16, 16), 256, 0, stream>>>(ws_Ab, ws_WreT, bre, out);
}

// Round 5
// 75.925 us; speedup vs baseline: 3.7744x; 1.1640x over previous
//
#include <hip/hip_runtime.h>

// Problem constants: B=2,S=512,E=1024; G=4,H=8,Q=16,D=2,V=16,N=512
// bgh = (b*4+g)*8+h in [0,64); sd in [0,1024); n in [0,512)

typedef __attribute__((ext_vector_type(4))) short bf16x4;
typedef __attribute__((ext_vector_type(8))) short short8;
typedef __attribute__((ext_vector_type(8))) unsigned short ushort8;
typedef __attribute__((ext_vector_type(8))) __bf16 bf16x8_t;
typedef __attribute__((ext_vector_type(4))) float f32x4;

static __device__ __forceinline__ unsigned short f2bf(float f) {
  union { float f; unsigned u; } v; v.f = f;
  unsigned r = v.u + 0x7fffu + ((v.u >> 16) & 1u);
  return (unsigned short)(r >> 16);
}

#if defined(__has_builtin)
#if __has_builtin(__builtin_amdgcn_mfma_f32_16x16x16bf16_1k)
#define HAVE_MFMA16 1
#endif
#if __has_builtin(__builtin_amdgcn_mfma_f32_16x16x32_bf16)
#define HAVE_MFMA32 1
#endif
#endif

static __device__ __forceinline__ f32x4 mfma16(bf16x4 a, bf16x4 b, f32x4 c) {
#ifdef HAVE_MFMA16
  return __builtin_amdgcn_mfma_f32_16x16x16bf16_1k(a, b, c, 0, 0, 0);
#else
  f32x4 d;
  asm volatile("v_mfma_f32_16x16x16_bf16 %0, %1, %2, %3\n\t"
               "s_nop 7\n\ts_nop 7"
               : "=&v"(d)
               : "v"(a), "v"(b), "v"(c));
  return d;
#endif
}

#ifdef HAVE_MFMA32
static __device__ __forceinline__ f32x4 mfma32(short8 a, short8 b, f32x4 c) {
  return __builtin_amdgcn_mfma_f32_16x16x32_bf16(
      __builtin_bit_cast(bf16x8_t, a), __builtin_bit_cast(bf16x8_t, b), c, 0, 0, 0);
}
#endif

// ---------------------------------------------------------------------------
// Prep (single launch, 1088 blocks):
//   [0,256)    : Wq  f32 -> WqT[n][k] bf16 (64x64 tile transpose)
//   [256,512)  : Wre f32 -> WreT[n][k] bf16
//   [512,576)  : keys/values -> KTb[bgh][n][16q], VTb[bgh][16v][512n] bf16
//   [576,1088) : emb f32 -> bf16 (straight convert)
// ---------------------------------------------------------------------------
__global__ __launch_bounds__(256) void prep_all(
    const float* __restrict__ Wq, const float* __restrict__ Wre,
    const float* __restrict__ keys, const float* __restrict__ values,
    const float* __restrict__ emb,
    unsigned short* __restrict__ WqT, unsigned short* __restrict__ WreT,
    unsigned short* __restrict__ KTb, unsigned short* __restrict__ VTb,
    unsigned short* __restrict__ embb) {
  __shared__ __align__(16) unsigned short t[64][72];
  const int blk = blockIdx.x;
  const int tid = threadIdx.x;

  if (blk < 512) {
    const float* W = (blk < 256) ? Wq : Wre;
    unsigned short* WT = (blk < 256) ? WqT : WreT;
    const int idx = blk & 255;
    const int bx = (idx & 15) * 64, by = (idx >> 4) * 64;
    const int r = tid >> 2;
    const int c0 = (tid & 3) * 16;
#pragma unroll
    for (int j = 0; j < 16; j += 4) {
      float4 v = *reinterpret_cast<const float4*>(&W[(long)(by + r) * 1024 + bx + c0 + j]);
      t[c0 + j + 0][r] = f2bf(v.x);
      t[c0 + j + 1][r] = f2bf(v.y);
      t[c0 + j + 2][r] = f2bf(v.z);
      t[c0 + j + 3][r] = f2bf(v.w);
    }
    __syncthreads();
#pragma unroll
    for (int j = 0; j < 16; j += 8) {
      *reinterpret_cast<ushort8*>(&WT[(long)(bx + r) * 1024 + by + c0 + j]) =
          *reinterpret_cast<const ushort8*>(&t[r][c0 + j]);
    }
  } else if (blk < 576) {
    const int kvIdx = blk - 512;
    const int bg = kvIdx >> 3, nb = kvIdx & 7;
    const long src_base = (long)bg * 512 * 128 + (long)nb * 64 * 128;
#pragma unroll
    for (int i = 0; i < 8; ++i) {
      int idx = tid + i * 256;
      int nl = idx >> 5, c4 = idx & 31;
      int n = nb * 64 + nl;
      float4 kv = *reinterpret_cast<const float4*>(&keys[src_base + nl * 128 + c4 * 4]);
      float4 vv = *reinterpret_cast<const float4*>(&values[src_base + nl * 128 + c4 * 4]);
      float kk[4] = {kv.x, kv.y, kv.z, kv.w};
      float vl[4] = {vv.x, vv.y, vv.z, vv.w};
#pragma unroll
      for (int cc = 0; cc < 4; ++cc) {
        int col = c4 * 4 + cc;          // qq*8 + h
        int h = col & 7, qv = col >> 3;
        int bgh = bg * 8 + h;
        KTb[((long)bgh * 512 + n) * 16 + qv] = f2bf(kk[cc]);
        VTb[((long)bgh * 16 + qv) * 512 + n] = f2bf(vl[cc]);
      }
    }
  } else {
    const long i = ((long)(blk - 576) * 256 + tid) * 8;
    float4 a = *reinterpret_cast<const float4*>(&emb[i]);
    float4 b = *reinterpret_cast<const float4*>(&emb[i + 4]);
    ushort8 o;
    o[0] = f2bf(a.x); o[1] = f2bf(a.y); o[2] = f2bf(a.z); o[3] = f2bf(a.w);
    o[4] = f2bf(b.x); o[5] = f2bf(b.y); o[6] = f2bf(b.z); o[7] = f2bf(b.w);
    *reinterpret_cast<ushort8*>(&embb[i]) = o;
  }
}

// ---------------------------------------------------------------------------
// bf16 MFMA GEMM: C[1024,1024] = A[m][k] @ BT[n][k]^T + bias.
// Tile 32x32, BK=64, 128 threads = 2 waves (wave w owns M rows w*16..+16).
// Grid 1024 blocks = 4 blocks/CU -> 4 independent barrier domains per CU
// (the round-4 bottleneck was 1 block/CU, all waves stalling together).
// XCD-chunked tile id keeps each XCD's panel set inside its private L2.
// LDS [32][72] padded (stride 36 dw): b128 wave access is bank-uniform.
// MODE 0: f32 row-major store + bias. MODE 1: bf16 scatter to qT layout.
// ---------------------------------------------------------------------------
template <int MODE>
__global__ __launch_bounds__(128) void gemm_bf16(
    const unsigned short* __restrict__ A, const unsigned short* __restrict__ BT,
    const float* __restrict__ bias, void* __restrict__ Cout) {
  __shared__ __align__(16) unsigned short As[2][32][72];
  __shared__ __align__(16) unsigned short Bs[2][32][72];
  const int tid = threadIdx.x;
  const int bid = blockIdx.x;
  const int tile = ((bid & 7) << 7) | (bid >> 3);   // XCD-chunked, bijective
  const int brow = (tile >> 5) << 5, bcol = (tile & 31) << 5;
  const int lane = tid & 63, w = tid >> 6;
  const int fr = lane & 15, kg = lane >> 4;

  const int r0 = tid >> 3;          // 0..15
  const int r1 = r0 + 16;           // 16..31
  const int c0 = (tid & 7) * 8;     // k-chunk (shorts)

  const unsigned short* ap0 = A + (long)(brow + r0) * 1024 + c0;
  const unsigned short* ap1 = A + (long)(brow + r1) * 1024 + c0;
  const unsigned short* bp0 = BT + (long)(bcol + r0) * 1024 + c0;
  const unsigned short* bp1 = BT + (long)(bcol + r1) * 1024 + c0;

  f32x4 acc[2] = {{0.f, 0.f, 0.f, 0.f}, {0.f, 0.f, 0.f, 0.f}};

  ushort8 sa0 = *reinterpret_cast<const ushort8*>(ap0);
  ushort8 sa1 = *reinterpret_cast<const ushort8*>(ap1);
  ushort8 sb0 = *reinterpret_cast<const ushort8*>(bp0);
  ushort8 sb1 = *reinterpret_cast<const ushort8*>(bp1);
  int buf = 0;
  for (int kt = 0; kt < 1024; kt += 64) {
    *reinterpret_cast<ushort8*>(&As[buf][r0][c0]) = sa0;
    *reinterpret_cast<ushort8*>(&As[buf][r1][c0]) = sa1;
    *reinterpret_cast<ushort8*>(&Bs[buf][r0][c0]) = sb0;
    *reinterpret_cast<ushort8*>(&Bs[buf][r1][c0]) = sb1;
    __syncthreads();
    if (kt + 64 < 1024) {
      sa0 = *reinterpret_cast<const ushort8*>(ap0 + kt + 64);
      sa1 = *reinterpret_cast<const ushort8*>(ap1 + kt + 64);
      sb0 = *reinterpret_cast<const ushort8*>(bp0 + kt + 64);
      sb1 = *reinterpret_cast<const ushort8*>(bp1 + kt + 64);
    }
#ifdef HAVE_MFMA32
    short8 alo = *reinterpret_cast<const short8*>(&As[buf][(w << 4) + fr][kg * 8]);
    short8 ahi = *reinterpret_cast<const short8*>(&As[buf][(w << 4) + fr][32 + kg * 8]);
    short8 b0lo = *reinterpret_cast<const short8*>(&Bs[buf][fr][kg * 8]);
    short8 b0hi = *reinterpret_cast<const short8*>(&Bs[buf][fr][32 + kg * 8]);
    short8 b1lo = *reinterpret_cast<const short8*>(&Bs[buf][16 + fr][kg * 8]);
    short8 b1hi = *reinterpret_cast<const short8*>(&Bs[buf][16 + fr][32 + kg * 8]);
    acc[0] = mfma32(alo, b0lo, acc[0]);
    acc[1] = mfma32(alo, b1lo, acc[1]);
    acc[0] = mfma32(ahi, b0hi, acc[0]);
    acc[1] = mfma32(ahi, b1hi, acc[1]);
#else
#pragma unroll
    for (int kq = 0; kq < 4; ++kq) {
      bf16x4 a = *reinterpret_cast<const bf16x4*>(&As[buf][(w << 4) + fr][kq * 16 + kg * 4]);
      bf16x4 b0 = *reinterpret_cast<const bf16x4*>(&Bs[buf][fr][kq * 16 + kg * 4]);
      bf16x4 b1 = *reinterpret_cast<const bf16x4*>(&Bs[buf][16 + fr][kq * 16 + kg * 4]);
      acc[0] = mfma16(a, b0, acc[0]);
      acc[1] = mfma16(a, b1, acc[1]);
    }
#endif
    buf ^= 1;
  }

  const int mrow = brow + (w << 4) + kg * 4;
  if (MODE == 0) {
    float* C = (float*)Cout;
#pragma unroll
    for (int n = 0; n < 2; ++n) {
      const int colc = bcol + n * 16 + fr;
      const float bv = bias[colc];
#pragma unroll
      for (int j = 0; j < 4; ++j)
        C[(long)(mrow + j) * 1024 + colc] = acc[n][j] + bv;
    }
  } else {
    unsigned short* C = (unsigned short*)Cout;
#pragma unroll
    for (int n = 0; n < 2; ++n) {
      const int colc = bcol + n * 16 + fr;
      const float bv = bias[colc];
      const int h = colc & 7, qqi = (colc >> 3) & 15, chi = colc >> 7;
#pragma unroll
      for (int j = 0; j < 4; ++j) {
        int row = mrow + j;
        int b = row >> 9, s = row & 511, g = s >> 7;
        int sd = (s & 127) * 8 + chi;
        int bgh = b * 32 + g * 8 + h;
        C[((long)bgh * 1024 + sd) * 16 + qqi] = f2bf(acc[n][j] + bv);
      }
    }
  }
}

// ---------------------------------------------------------------------------
// MFMA flash attention. Block = 4 waves; wave w owns sd-tile
// [rb*64 + w*16, +16) of one bgh. Swapped-operand scheme:
//   S^T[n][sd] = mfma(A=K[n][q], B=Q^T[q][sd]); online softmax (column-local);
//   O^T[v][sd] = mfma(A=V^T[v][n], B=P^T[n][sd])  — S^T C-layout == P^T B-layout.
// conn_sub (134 MB, the dominant stream) read as float4 straight to registers.
// ---------------------------------------------------------------------------
__global__ __launch_bounds__(256) void attn_mfma(
    const unsigned short* __restrict__ qTb, const unsigned short* __restrict__ KTb,
    const unsigned short* __restrict__ VTb, const float* __restrict__ conn,
    float* __restrict__ ln_in) {
  __shared__ float O_lds[4][16][17];

  const int tid = threadIdx.x;
  const int wid = tid >> 6, lane = tid & 63;
  const int c = lane & 15, hi = lane >> 4;
  const int rb = blockIdx.x;
  const int bgh = blockIdx.y;
  const int b = bgh >> 5, g = (bgh >> 3) & 3, h = bgh & 7;
  const int sd = rb * 64 + wid * 16 + c;

  bf16x4 qb = *reinterpret_cast<const bf16x4*>(&qTb[((long)bgh * 1024 + sd) * 16 + hi * 4]);

  const unsigned short* kp = KTb + (long)bgh * 8192 + hi * 4;
  const unsigned short* vp = VTb + (long)bgh * 8192 + (long)c * 512 + hi * 4;
  const float* cp = conn + ((long)bgh * 1024 + sd) * 512 + hi * 4;

  f32x4 acc = {0.f, 0.f, 0.f, 0.f};
  float m = -1e30f, lsum = 0.f;

  for (int nb = 0; nb < 512; nb += 64) {
    f32x4 sv[4];
    float cv[16];
    const f32x4 zero = {0.f, 0.f, 0.f, 0.f};
#pragma unroll
    for (int t = 0; t < 4; ++t) {
      const int n0 = nb + t * 16;
      bf16x4 ka = *reinterpret_cast<const bf16x4*>(kp + (long)(n0 + c) * 16);
      float4 cf = *reinterpret_cast<const float4*>(cp + n0);
      sv[t] = mfma16(ka, qb, zero);
      cv[t * 4 + 0] = cf.x;
      cv[t * 4 + 1] = cf.y;
      cv[t * 4 + 2] = cf.z;
      cv[t * 4 + 3] = cf.w;
    }
    float s[16];
#pragma unroll
    for (int t = 0; t < 4; ++t)
#pragma unroll
      for (int r = 0; r < 4; ++r) s[t * 4 + r] = sv[t][r] * 0.25f - cv[t * 4 + r];

    float cmax = s[0];
#pragma unroll
    for (int j = 1; j < 16; ++j) cmax = fmaxf(cmax, s[j]);
    cmax = fmaxf(cmax, __shfl_xor(cmax, 16, 64));
    cmax = fmaxf(cmax, __shfl_xor(cmax, 32, 64));
    const float mnew = fmaxf(m, cmax);
    const float fac = __expf(m - mnew);
    acc *= fac;
    lsum *= fac;
    float p[16];
    float csum = 0.f;
#pragma unroll
    for (int j = 0; j < 16; ++j) {
      p[j] = __expf(s[j] - mnew);
      csum += p[j];
    }
    lsum += csum;
    m = mnew;
#pragma unroll
    for (int t = 0; t < 4; ++t) {
      const int n0 = nb + t * 16;
      bf16x4 pb;
      pb[0] = (short)f2bf(p[t * 4 + 0]);
      pb[1] = (short)f2bf(p[t * 4 + 1]);
      pb[2] = (short)f2bf(p[t * 4 + 2]);
      pb[3] = (short)f2bf(p[t * 4 + 3]);
      bf16x4 va = *reinterpret_cast<const bf16x4*>(vp + n0);
      acc = mfma16(va, pb, acc);
    }
  }

  lsum += __shfl_xor(lsum, 16, 64);
  lsum += __shfl_xor(lsum, 32, 64);
  const float rinv = 1.0f / lsum;
#pragma unroll
  for (int r = 0; r < 4; ++r) O_lds[wid][c][hi * 4 + r] = acc[r] * rinv;
  __syncthreads();

  const int dd = (rb * 64) >> 9;
  const int chb = g * 256 + h * 32 + dd * 16;
#pragma unroll
  for (int pass = 0; pass < 4; ++pass) {
    int rr = pass * 16 + (tid >> 4);
    int v = tid & 15;
    int ssi = (rb * 64 + rr) & 511;
    ln_in[(long)(b * 512 + ssi) * 1024 + chb + v] = O_lds[rr >> 4][rr & 15][v];
  }
}

// ---------------------------------------------------------------------------
// LayerNorm over last dim (1024); reads f32, writes bf16 (A of final GEMM).
// ---------------------------------------------------------------------------
__global__ __launch_bounds__(256) void ln_kernel(
    const float* __restrict__ x, const float* __restrict__ gamma,
    const float* __restrict__ beta, unsigned short* __restrict__ out) {
  const int row = blockIdx.x;
  const int tid = threadIdx.x;
  float4 v = *reinterpret_cast<const float4*>(&x[(long)row * 1024 + tid * 4]);
  float s = v.x + v.y + v.z + v.w;
  float s2 = v.x * v.x + v.y * v.y + v.z * v.z + v.w * v.w;
#pragma unroll
  for (int w = 32; w >= 1; w >>= 1) {
    s += __shfl_xor(s, w, 64);
    s2 += __shfl_xor(s2, w, 64);
  }
  __shared__ float red[8];
  const int lane = tid & 63, wid = tid >> 6;
  if (lane == 0) {
    red[wid] = s;
    red[wid + 4] = s2;
  }
  __syncthreads();
  s = red[0] + red[1] + red[2] + red[3];
  s2 = red[4] + red[5] + red[6] + red[7];
  const float mu = s * (1.0f / 1024.0f);
  const float var = s2 * (1.0f / 1024.0f) - mu * mu;
  const float rstd = rsqrtf(var + 1e-5f);
  float4 g4 = *reinterpret_cast<const float4*>(&gamma[tid * 4]);
  float4 b4 = *reinterpret_cast<const float4*>(&beta[tid * 4]);
  unsigned short o[4];
  o[0] = f2bf((v.x - mu) * rstd * g4.x + b4.x);
  o[1] = f2bf((v.y - mu) * rstd * g4.y + b4.y);
  o[2] = f2bf((v.z - mu) * rstd * g4.z + b4.z);
  o[3] = f2bf((v.w - mu) * rstd * g4.w + b4.w);
  *reinterpret_cast<uint2*>(&out[(long)row * 1024 + tid * 4]) = *reinterpret_cast<uint2*>(o);
}

// ---------------------------------------------------------------------------
extern "C" void kernel_launch(void* const* d_in, const int* in_sizes, int n_in,
                              void* d_out, int out_size, void* d_ws,
                              size_t ws_size, hipStream_t stream) {
  const float* emb = (const float*)d_in[0];
  const float* keys = (const float*)d_in[1];
  const float* values = (const float*)d_in[2];
  const float* conn = (const float*)d_in[3];
  const float* Wq = (const float*)d_in[4];
  const float* bq = (const float*)d_in[5];
  const float* ln_g = (const float*)d_in[6];
  const float* ln_b = (const float*)d_in[7];
  const float* Wre = (const float*)d_in[8];
  const float* bre = (const float*)d_in[9];
  float* out = (float*)d_out;

  // workspace (14 MB):
  char* w = (char*)d_ws;
  float* ws_ln = (float*)w;                                         // 4 MB
  unsigned short* ws_Ab = (unsigned short*)(w + 4 * 1024 * 1024);   // 2 MB (emb bf16, later ln bf16)
  unsigned short* ws_WqT = (unsigned short*)(w + 6 * 1024 * 1024);  // 2 MB
  unsigned short* ws_WreT = (unsigned short*)(w + 8 * 1024 * 1024); // 2 MB
  unsigned short* ws_qTb = (unsigned short*)(w + 10 * 1024 * 1024); // 2 MB
  unsigned short* ws_KTb = (unsigned short*)(w + 12 * 1024 * 1024); // 1 MB
  unsigned short* ws_VTb = (unsigned short*)(w + 13 * 1024 * 1024); // 1 MB

  prep_all<<<1088, 256, 0, stream>>>(Wq, Wre, keys, values, emb,
                                     ws_WqT, ws_WreT, ws_KTb, ws_VTb, ws_Ab);
  gemm_bf16<1><<<1024, 128, 0, stream>>>(ws_Ab, ws_WqT, bq, ws_qTb);
  attn_mfma<<<dim3(16, 64), 256, 0, stream>>>(ws_qTb, ws_KTb, ws_VTb, conn, ws_ln);
  ln_kernel<<<1024, 256, 0, stream>>>(ws_ln, ln_g, ln_b, ws_Ab);
  gemm_bf16<0><<<1024, 128, 0, stream>>>(ws_Ab, ws_WreT, bre, out);
}